// Round 10
// baseline (274.491 us; speedup 1.0000x reference)
//
#include <hip/hip_runtime.h>
#include <hip/hip_cooperative_groups.h>
#include <math.h>

namespace cg = cooperative_groups;

#define NN 2048
#define BB 16
#define T1D 12
#define T2D 64
#define JJ 192   // packed columns (b*12+u)

typedef short short8 __attribute__((ext_vector_type(8)));
typedef float f32x4 __attribute__((ext_vector_type(4)));

// workspace layout in floats (~13 MB total)
#define OFF_DIS   0
#define OFF_E     2048                    // 2304 floats (16 x 144)
#define OFF_XH    4608
#define OFF_P1    (OFF_XH + NN*JJ)
#define OFF_XHBT  (OFF_P1 + NN*JJ)        // ushort buf, NN*JJ/2 floats
#define OFF_P1BT  (OFF_XHBT + NN*JJ/2)
#define OFF_ABT   (OFF_P1BT + NN*JJ/2)    // 2048*2048 ushort

__device__ inline ushort f2bf(float f) {
    union { float f; unsigned int u; } x; x.f = f;
    unsigned int u = x.u + 0x7fffu + ((x.u >> 16) & 1u);
    return (ushort)(u >> 16);
}

// ==== shared GEMM body: tile[c0..+16][j0..+48] = sum_k AbT[c][k]*Zbt[j][k] ===
// blk2 in [0,512): c0=(blk2>>2)*16, j0=(blk2&3)*48. 512 thr = 8 waves, wave w
// owns K [w*256,+256). MODE 0: write P fp32 + Pbt bf16-transposed.
// MODE 1: fused Chebyshev epilogue writes out (4 batches), no global P.
template<int MODE>
__device__ __forceinline__ void gemm_body(int blk2, int tid, float* lds,
                                          const ushort* __restrict__ AbT,
                                          const ushort* __restrict__ Zbt,
                                          float* __restrict__ P,
                                          ushort* __restrict__ Pbt,
                                          const float* __restrict__ P1,
                                          const float* __restrict__ Xh,
                                          const float* __restrict__ Wcheb,
                                          const float* __restrict__ bcheb,
                                          float* __restrict__ out) {
    float* Pred = lds + 6144;
    int wave = tid >> 6, lane = tid & 63;
    int jl = lane & 15;
    int kl = (lane >> 4) * 8;
    int c0 = (blk2 >> 2) * 16;
    int j0 = (blk2 & 3) * 48;
    int kbase = wave * 256 + kl;

    const ushort* arow = AbT + (size_t)(c0 + jl) * NN + kbase;
    f32x4 acc[3];
#pragma unroll
    for (int n = 0; n < 3; ++n) acc[n] = (f32x4)0.f;

#pragma unroll
    for (int ch = 0; ch < 8; ++ch) {
        int koff = ch * 32;
        short8 a = *(const short8*)&arow[koff];
        short8 bfr[3];
#pragma unroll
        for (int n = 0; n < 3; ++n)
            bfr[n] = *(const short8*)&Zbt[(size_t)(j0 + n * 16 + jl) * NN + kbase + koff];
#pragma unroll
        for (int n = 0; n < 3; ++n)
            acc[n] = __builtin_amdgcn_mfma_f32_16x16x32_bf16(a, bfr[n], acc[n], 0, 0, 0);
    }

#pragma unroll
    for (int n = 0; n < 3; ++n)
        *(f32x4*)&lds[((wave * 3 + n) << 8) + (lane << 2)] = acc[n];
    __syncthreads();

    // reduce 8 wave-partials -> Pred[16][48]; MODE 0 also stores P fp32
    for (int o = tid; o < 768; o += 512) {
        int c_idx = o / 48;
        int j_idx = o - c_idx * 48;
        int n = j_idx >> 4, col = j_idx & 15;
        int lidx = ((c_idx >> 2) * 16 + col) * 4 + (c_idx & 3);
        float s = 0.f;
#pragma unroll
        for (int w = 0; w < 8; ++w) s += lds[(w * 3 + n) * 256 + lidx];
        Pred[c_idx * 48 + j_idx] = s;
        if (MODE == 0) P[(size_t)(c0 + c_idx) * JJ + j0 + j_idx] = s;
    }
    __syncthreads();

    if (MODE == 0) {
        // bf16 transpose: Pbt[j0+j][c0..c0+16]
        if (tid < 48) {
            union { ushort us[8]; uint4 v; } q0, q1;
#pragma unroll
            for (int e = 0; e < 8; ++e) q0.us[e] = f2bf(Pred[e * 48 + tid]);
#pragma unroll
            for (int e = 0; e < 8; ++e) q1.us[e] = f2bf(Pred[(8 + e) * 48 + tid]);
            *(uint4*)&Pbt[(size_t)(j0 + tid) * NN + c0] = q0.v;
            *(uint4*)&Pbt[(size_t)(j0 + tid) * NN + c0 + 8] = q1.v;
        }
    } else {
        // out = relu(Xh(W0-W2) - P1*W1 + 2*P2*W2 + bcheb)
        int o = tid & 63, pair = tid >> 6;
        const float* W0 = Wcheb;
        const float* W1 = Wcheb + 768;
        const float* W2 = Wcheb + 1536;
        float w0m2[T1D], w1a[T1D], w2a[T1D];
#pragma unroll
        for (int t = 0; t < T1D; ++t) {
            float w2v = W2[t * 64 + o];
            w0m2[t] = W0[t * 64 + o] - w2v;
            w1a[t] = W1[t * 64 + o];
            w2a[t] = 2.f * w2v;
        }
        float bco = bcheb[o];
#pragma unroll
        for (int it = 0; it < 8; ++it) {
            int pi = pair + it * 8;            // 0..63
            int ni = pi >> 2, bi = pi & 3;
            int n = c0 + ni;
            int b = (blk2 & 3) * 4 + bi;
            const float* xh = Xh + (size_t)n * JJ + b * T1D;
            const float* p1 = P1 + (size_t)n * JJ + b * T1D;
            const float* p2 = Pred + ni * 48 + bi * T1D;
            float a = bco;
#pragma unroll
            for (int t = 0; t < T1D; ++t)
                a += xh[t] * w0m2[t] - p1[t] * w1a[t] + p2[t] * w2a[t];
            out[(size_t)((b << 11) + n) * 64 + o] = fmaxf(a, 0.f);
        }
    }
}

// ==== cooperative mega-kernel: 256 blocks x 512 thr (1 block/CU) =============
__global__ __launch_bounds__(512, 2) void k_mega(
        const float* __restrict__ A, const float* __restrict__ X,
        const float* __restrict__ U1, const float* __restrict__ U2,
        const float* __restrict__ U3, const float* __restrict__ be,
        const float* __restrict__ Ve, const float* __restrict__ Wc,
        const float* __restrict__ bc,
        float* __restrict__ dis, float* __restrict__ E_ws,
        float* __restrict__ Xh, float* __restrict__ P1,
        ushort* __restrict__ Xhbt, ushort* __restrict__ P1bt,
        ushort* __restrict__ AbT, float* __restrict__ out) {
    cg::grid_group grid = cg::this_grid();
    __shared__ float lds[6912];               // 27.6 KB
    int tid = threadIdx.x;
    int blk = blockIdx.x;

    // ---------- phase 0: deg (all blocks, 8 rows) + E prep (blocks 0..15) ----
    {
        int wave = tid >> 6, lane = tid & 63;
        int r = blk * 8 + wave;
        const float4* Ar = (const float4*)(A + (size_t)r * NN);
        float s = 0.f;
#pragma unroll
        for (int i = 0; i < 8; ++i) {
            float4 v = Ar[i * 64 + lane];
            s += v.x + v.y + v.z + v.w;
        }
#pragma unroll
        for (int off = 32; off > 0; off >>= 1) s += __shfl_down(s, off);
        if (lane == 0) dis[r] = (s > 0.f) ? rsqrtf(s) : 0.f;
    }
    if (blk < 16) {
        int b = blk;
        float accr[T1D], accc[T1D];
#pragma unroll
        for (int t = 0; t < T1D; ++t) { accr[t] = 0.f; accc[t] = 0.f; }
        for (int n = tid; n < NN; n += 512) {
            const float* xp = X + ((size_t)b * NN + n) * T1D;
            float x[T1D];
            *(float4*)&x[0] = *(const float4*)&xp[0];
            *(float4*)&x[4] = *(const float4*)&xp[4];
            *(float4*)&x[8] = *(const float4*)&xp[8];
            float u1 = U1[n], u2 = U2[n];
#pragma unroll
            for (int t = 0; t < T1D; ++t) {
                accr[t] += x[t] * u1;
                accc[t] += x[t] * u2;
            }
        }
#pragma unroll
        for (int off = 32; off > 0; off >>= 1) {
#pragma unroll
            for (int t = 0; t < T1D; ++t) {
                accr[t] += __shfl_down(accr[t], off);
                accc[t] += __shfl_down(accc[t], off);
            }
        }
        float* red24  = lds;          // [24][8]
        float* es     = lds + 192;    // [144]
        float* redtot = lds + 352;    // [24]
        int wave = tid >> 6, lane = tid & 63;
        if (lane == 0) {
#pragma unroll
            for (int t = 0; t < T1D; ++t) {
                red24[t * 8 + wave] = accr[t];
                red24[(12 + t) * 8 + wave] = accc[t];
            }
        }
        __syncthreads();
        if (tid < 24) {
            float s = 0.f;
#pragma unroll
            for (int w = 0; w < 8; ++w) s += red24[tid * 8 + w];
            redtot[tid] = s;
        }
        __syncthreads();
        float u3 = U3[0];
        if (tid < T1D) {              // softmax over t per column s
            int s = tid;
            float cs = redtot[12 + s] * u3;
            float vals[T1D];
            float m = -1e30f;
#pragma unroll
            for (int t = 0; t < T1D; ++t) {
                vals[t] = redtot[t] * cs + be[t * T1D + s];
                m = fmaxf(m, vals[t]);
            }
            float sum = 0.f;
#pragma unroll
            for (int t = 0; t < T1D; ++t) { vals[t] = expf(vals[t] - m); sum += vals[t]; }
            float inv = 1.f / sum;
#pragma unroll
            for (int t = 0; t < T1D; ++t) es[t * T1D + s] = vals[t] * inv;
        }
        __syncthreads();
        if (tid < T1D) {              // Ve @ es, softmax over t, store E
            int u = tid;
            float vals[T1D];
            float m = -1e30f;
#pragma unroll
            for (int t = 0; t < T1D; ++t) {
                float acc = 0.f;
#pragma unroll
                for (int s = 0; s < T1D; ++s) acc += Ve[t * T1D + s] * es[s * T1D + u];
                vals[t] = acc;
                m = fmaxf(m, acc);
            }
            float sum = 0.f;
#pragma unroll
            for (int t = 0; t < T1D; ++t) { vals[t] = expf(vals[t] - m); sum += vals[t]; }
            float inv = 1.f / sum;
#pragma unroll
            for (int t = 0; t < T1D; ++t) E_ws[b * 144 + t * T1D + u] = vals[t] * inv;
        }
    }
    grid.sync();

    // ---------- phase 1: AbT convert (4 tiles/block) + Xh (8 rows/block) -----
#pragma unroll 1
    for (int tt = 0; tt < 4; ++tt) {
        int tile = blk * 4 + tt;
        int c0 = (tile & 31) * 64, k0 = (tile >> 5) * 64;
        __syncthreads();
#pragma unroll
        for (int i = 0; i < 2; ++i) {
            int idx = tid + i * 512;          // < 1024
            int kr = idx >> 4, c4 = idx & 15;
            float4 v = *(const float4*)&A[(size_t)(k0 + kr) * NN + c0 + c4 * 4];
            float dk = dis[k0 + kr];
            lds[(c4 * 4 + 0) * 65 + kr] = v.x * dk;
            lds[(c4 * 4 + 1) * 65 + kr] = v.y * dk;
            lds[(c4 * 4 + 2) * 65 + kr] = v.z * dk;
            lds[(c4 * 4 + 3) * 65 + kr] = v.w * dk;
        }
        __syncthreads();
        int cl = tid >> 3, ck = (tid & 7) * 8;
        float dc = dis[c0 + cl];
        union { ushort us[8]; uint4 v; } p;
#pragma unroll
        for (int e = 0; e < 8; ++e) p.us[e] = f2bf(lds[cl * 65 + ck + e] * dc);
        *(uint4*)&AbT[(size_t)(c0 + cl) * NN + k0 + ck] = p.v;
    }
    {
        __syncthreads();
        int n0 = blk * 8;
        float* EL = lds + 4352;               // E copy: 2304 floats
#pragma unroll
        for (int i = 0; i < 5; ++i) {
            int idx = tid + i * 512;
            if (idx < 2304) EL[idx] = E_ws[idx];
        }
        __syncthreads();
        if (tid < 128) {
            int nr = tid >> 4, b = tid & 15;
            const float* xp = X + ((size_t)b * NN + n0 + nr) * T1D;
            float x[T1D];
            *(float4*)&x[0] = *(const float4*)&xp[0];
            *(float4*)&x[4] = *(const float4*)&xp[4];
            *(float4*)&x[8] = *(const float4*)&xp[8];
            const float* Eb = EL + b * 144;
#pragma unroll
            for (int u = 0; u < T1D; ++u) {
                float acc = 0.f;
#pragma unroll
                for (int t2 = 0; t2 < T1D; ++t2) acc += x[t2] * Eb[t2 * T1D + u];
                lds[nr * 200 + b * T1D + u] = acc;
            }
        }
        __syncthreads();
        if (tid < 384) {
            int row = tid / 48, c4 = tid % 48;
            *(float4*)&Xh[(size_t)(n0 + row) * JJ + c4 * 4] =
                *(float4*)&lds[row * 200 + c4 * 4];
        }
        if (tid < JJ) {
            union { ushort us[8]; uint4 v; } p0;
#pragma unroll
            for (int nr = 0; nr < 8; ++nr) p0.us[nr] = f2bf(lds[nr * 200 + tid]);
            *(uint4*)&Xhbt[(size_t)tid * NN + n0] = p0.v;
        }
    }
    grid.sync();

    // ---------- phase 2: GEMM1 (P1 = Asc^T Xh), writes P1 + P1bt -------------
#pragma unroll 1
    for (int s = 0; s < 2; ++s) {
        __syncthreads();
        gemm_body<0>(blk * 2 + s, tid, lds, AbT, Xhbt, P1, P1bt,
                     nullptr, nullptr, nullptr, nullptr, nullptr);
    }
    grid.sync();

    // ---------- phase 3: GEMM2 (P2 = Asc^T P1) + fused Chebyshev epilogue ----
#pragma unroll 1
    for (int s = 0; s < 2; ++s) {
        __syncthreads();
        gemm_body<1>(blk * 2 + s, tid, lds, AbT, P1bt, nullptr, nullptr,
                     P1, Xh, Wc, bc, out);
    }
}

// ======================= fallback path (round-6, proven) =====================
__global__ __launch_bounds__(256) void k_degE(const float* __restrict__ A,
                                              const float* __restrict__ X,
                                              const float* __restrict__ U1,
                                              const float* __restrict__ U2,
                                              const float* __restrict__ U3,
                                              const float* __restrict__ be,
                                              const float* __restrict__ Ve,
                                              float* __restrict__ dis,
                                              float* __restrict__ E_ws) {
    __shared__ float red[24][256];
    __shared__ float es[T1D][T1D];
    int tid = threadIdx.x;

    if (blockIdx.x < 512) {
        int wid = tid >> 6, lane = tid & 63;
        int r = blockIdx.x * 4 + wid;
        const float4* Ar = (const float4*)(A + (size_t)r * NN);
        float s = 0.f;
#pragma unroll
        for (int i = 0; i < 8; ++i) {
            float4 v = Ar[i * 64 + lane];
            s += v.x + v.y + v.z + v.w;
        }
#pragma unroll
        for (int off = 32; off > 0; off >>= 1) s += __shfl_down(s, off);
        if (lane == 0) dis[r] = (s > 0.f) ? rsqrtf(s) : 0.f;
        return;
    }

    int b = blockIdx.x - 512;
    float accr[T1D], accc[T1D];
#pragma unroll
    for (int t = 0; t < T1D; ++t) { accr[t] = 0.f; accc[t] = 0.f; }
    for (int n = tid; n < NN; n += 256) {
        const float* xp = X + ((size_t)b * NN + n) * T1D;
        float x[T1D];
        *(float4*)&x[0] = *(const float4*)&xp[0];
        *(float4*)&x[4] = *(const float4*)&xp[4];
        *(float4*)&x[8] = *(const float4*)&xp[8];
        float u1 = U1[n], u2 = U2[n];
#pragma unroll
        for (int t = 0; t < T1D; ++t) {
            accr[t] += x[t] * u1;
            accc[t] += x[t] * u2;
        }
    }
#pragma unroll
    for (int t = 0; t < T1D; ++t) {
        red[t][tid] = accr[t];
        red[12 + t][tid] = accc[t];
    }
    __syncthreads();
    for (int s = 128; s > 0; s >>= 1) {
        if (tid < s) {
#pragma unroll
            for (int a = 0; a < 24; ++a) red[a][tid] += red[a][tid + s];
        }
        __syncthreads();
    }
    float u3 = U3[0];
    if (tid < T1D) {
        int s = tid;
        float cs = red[12 + s][0] * u3;
        float vals[T1D];
        float m = -1e30f;
#pragma unroll
        for (int t = 0; t < T1D; ++t) {
            vals[t] = red[t][0] * cs + be[t * T1D + s];
            m = fmaxf(m, vals[t]);
        }
        float sum = 0.f;
#pragma unroll
        for (int t = 0; t < T1D; ++t) { vals[t] = expf(vals[t] - m); sum += vals[t]; }
        float inv = 1.f / sum;
#pragma unroll
        for (int t = 0; t < T1D; ++t) es[t][s] = vals[t] * inv;
    }
    __syncthreads();
    if (tid < T1D) {
        int u = tid;
        float vals[T1D];
        float m = -1e30f;
#pragma unroll
        for (int t = 0; t < T1D; ++t) {
            float acc = 0.f;
#pragma unroll
            for (int s = 0; s < T1D; ++s) acc += Ve[t * T1D + s] * es[s][u];
            vals[t] = acc;
            m = fmaxf(m, acc);
        }
        float sum = 0.f;
#pragma unroll
        for (int t = 0; t < T1D; ++t) { vals[t] = expf(vals[t] - m); sum += vals[t]; }
        float inv = 1.f / sum;
#pragma unroll
        for (int t = 0; t < T1D; ++t) E_ws[b * 144 + t * T1D + u] = vals[t] * inv;
    }
}

__global__ __launch_bounds__(256) void k_mid(const float* __restrict__ A,
                                             const float* __restrict__ dis,
                                             const float* __restrict__ X,
                                             const float* __restrict__ E_ws,
                                             ushort* __restrict__ AbT,
                                             float* __restrict__ Xh,
                                             ushort* __restrict__ Xhbt) {
    __shared__ float lds[5504];
    int t = threadIdx.x;

    if (blockIdx.x < 1024) {
        int c0 = (blockIdx.x & 31) * 64, k0 = (blockIdx.x >> 5) * 64;
#pragma unroll
        for (int i = 0; i < 4; ++i) {
            int idx = t + i * 256;           // < 1024
            int kr = idx >> 4, c4 = idx & 15;
            float4 v = *(const float4*)&A[(size_t)(k0 + kr) * NN + c0 + c4 * 4];
            float dk = dis[k0 + kr];
            lds[(c4 * 4 + 0) * 65 + kr] = v.x * dk;
            lds[(c4 * 4 + 1) * 65 + kr] = v.y * dk;
            lds[(c4 * 4 + 2) * 65 + kr] = v.z * dk;
            lds[(c4 * 4 + 3) * 65 + kr] = v.w * dk;
        }
        __syncthreads();
        int cl = t >> 2, ck = (t & 3) * 16;
        float dc = dis[c0 + cl];
        union { ushort us[8]; uint4 v; } p0, p1;
#pragma unroll
        for (int e = 0; e < 8; ++e) p0.us[e] = f2bf(lds[cl * 65 + ck + e] * dc);
#pragma unroll
        for (int e = 0; e < 8; ++e) p1.us[e] = f2bf(lds[cl * 65 + ck + 8 + e] * dc);
        *(uint4*)&AbT[(size_t)(c0 + cl) * NN + k0 + ck] = p0.v;
        *(uint4*)&AbT[(size_t)(c0 + cl) * NN + k0 + ck + 8] = p1.v;
        return;
    }

    int n0 = (blockIdx.x - 1024) * 16;
    float* EL = lds + 3200;
#pragma unroll
    for (int i = 0; i < 9; ++i) {
        int idx = t + i * 256;
        if (idx < 2304) EL[idx] = E_ws[idx];
    }
    __syncthreads();
    {
        int nr = t >> 4, b = t & 15;
        const float* xp = X + ((size_t)b * NN + n0 + nr) * T1D;
        float x[T1D];
        *(float4*)&x[0] = *(const float4*)&xp[0];
        *(float4*)&x[4] = *(const float4*)&xp[4];
        *(float4*)&x[8] = *(const float4*)&xp[8];
        const float* Eb = EL + b * 144;
#pragma unroll
        for (int u = 0; u < T1D; ++u) {
            float acc = 0.f;
#pragma unroll
            for (int tt = 0; tt < T1D; ++tt) acc += x[tt] * Eb[tt * T1D + u];
            lds[nr * 200 + b * T1D + u] = acc;
        }
    }
    __syncthreads();
#pragma unroll
    for (int i = 0; i < 3; ++i) {
        int idx4 = t + i * 256;             // < 768
        int row = idx4 / 48, c4 = idx4 % 48;
        *(float4*)&Xh[(size_t)(n0 + row) * JJ + c4 * 4] =
            *(float4*)&lds[row * 200 + c4 * 4];
    }
    if (t < JJ) {
        union { ushort us[8]; uint4 v; } p0, p1;
#pragma unroll
        for (int nr = 0; nr < 8; ++nr) p0.us[nr] = f2bf(lds[nr * 200 + t]);
#pragma unroll
        for (int nr = 0; nr < 8; ++nr) p1.us[nr] = f2bf(lds[(8 + nr) * 200 + t]);
        *(uint4*)&Xhbt[(size_t)t * NN + n0] = p0.v;
        *(uint4*)&Xhbt[(size_t)t * NN + n0 + 8] = p1.v;
    }
}

template<int MODE>
__global__ __launch_bounds__(512) void k_gemm(const ushort* __restrict__ AbT,
                                              const ushort* __restrict__ Zbt,
                                              float* __restrict__ P,
                                              ushort* __restrict__ Pbt,
                                              const float* __restrict__ P1,
                                              const float* __restrict__ Xh,
                                              const float* __restrict__ Wcheb,
                                              const float* __restrict__ bcheb,
                                              float* __restrict__ out) {
    __shared__ float lds[8 * 3 * 256 + 16 * 48];
    int blk2 = blockIdx.x * 4 + blockIdx.y;
    gemm_body<MODE>(blk2, threadIdx.x, lds, AbT, Zbt, P, Pbt,
                    P1, Xh, Wcheb, bcheb, out);
}

extern "C" void kernel_launch(void* const* d_in, const int* in_sizes, int n_in,
                              void* d_out, int out_size, void* d_ws, size_t ws_size,
                              hipStream_t stream) {
    const float* X  = (const float*)d_in[0];
    const float* A  = (const float*)d_in[1];
    // d_in[2]=Vs, d_in[3]=bs, d_in[4]=W1, d_in[5]=W2, d_in[6]=W3 : dead code
    const float* Ve = (const float*)d_in[7];
    const float* be = (const float*)d_in[8];
    const float* U1 = (const float*)d_in[9];
    const float* U2 = (const float*)d_in[10];
    const float* U3 = (const float*)d_in[11];
    const float* Wc = (const float*)d_in[12];
    const float* bc = (const float*)d_in[13];
    float* out = (float*)d_out;

    float* w     = (float*)d_ws;
    float* dis   = w + OFF_DIS;
    float* E     = w + OFF_E;
    float* Xh    = w + OFF_XH;
    float* P1    = w + OFF_P1;
    ushort* Xhbt = (ushort*)(w + OFF_XHBT);
    ushort* P1bt = (ushort*)(w + OFF_P1BT);
    ushort* AbT  = (ushort*)(w + OFF_ABT);

    void* args[] = { (void*)&A, (void*)&X, (void*)&U1, (void*)&U2, (void*)&U3,
                     (void*)&be, (void*)&Ve, (void*)&Wc, (void*)&bc,
                     (void*)&dis, (void*)&E, (void*)&Xh, (void*)&P1,
                     (void*)&Xhbt, (void*)&P1bt, (void*)&AbT, (void*)&out };
    hipError_t err = hipLaunchCooperativeKernel((const void*)k_mega, dim3(256),
                                                dim3(512), args, 0, stream);
    if (err != hipSuccess) {
        // deterministic fallback: proven round-6 4-dispatch path
        k_degE<<<528, 256, 0, stream>>>(A, X, U1, U2, U3, be, Ve, dis, E);
        k_mid<<<1152, 256, 0, stream>>>(A, dis, X, E, AbT, Xh, Xhbt);
        k_gemm<0><<<dim3(128, 4), 512, 0, stream>>>(AbT, Xhbt, P1, P1bt,
                                                    nullptr, nullptr, nullptr,
                                                    nullptr, nullptr);
        k_gemm<1><<<dim3(128, 4), 512, 0, stream>>>(AbT, P1bt, nullptr, nullptr,
                                                    P1, Xh, Wc, bc, out);
    }
}

// Round 11
// 159.546 us; speedup vs baseline: 1.7204x; 1.7204x over previous
//
#include <hip/hip_runtime.h>
#include <math.h>

#define NN 2048
#define NNP 2080  // padded K-major row stride (ushort) — breaks 4KB power-of-2 L2 aliasing
#define BB 16
#define T1D 12
#define T2D 64
#define JJ 192   // packed columns (b*12+u)

typedef short short8 __attribute__((ext_vector_type(8)));
typedef float f32x4 __attribute__((ext_vector_type(4)));

// workspace layout in floats (~13.3 MB total)
#define OFF_DIS   0
#define OFF_E     2048                    // 2304 floats (16 x 144)
#define OFF_XH    4608
#define OFF_P1    (OFF_XH + NN*JJ)        // 397824
#define OFF_XHBT  (OFF_P1 + NN*JJ)        // ushort buf, JJ*NNP/2 floats
#define OFF_P1BT  (OFF_XHBT + JJ*NNP/2)
#define OFF_ABT   (OFF_P1BT + JJ*NNP/2)   // 2048*2080 ushort

__device__ inline ushort f2bf(float f) {
    union { float f; unsigned int u; } x; x.f = f;
    unsigned int u = x.u + 0x7fffu + ((x.u >> 16) & 1u);
    return (ushort)(u >> 16);
}

// ============ dispatch 1: deg rowsums (blocks 0..511) + E prep (512..527) ====
__global__ __launch_bounds__(256) void k_degE(const float* __restrict__ A,
                                              const float* __restrict__ X,
                                              const float* __restrict__ U1,
                                              const float* __restrict__ U2,
                                              const float* __restrict__ U3,
                                              const float* __restrict__ be,
                                              const float* __restrict__ Ve,
                                              float* __restrict__ dis,
                                              float* __restrict__ E_ws) {
    __shared__ float red[24][256];
    __shared__ float es[T1D][T1D];
    int tid = threadIdx.x;

    if (blockIdx.x < 512) {
        // ---- deg -> dis = rsqrt(rowsum(A)), one wave per row ----
        int wid = tid >> 6, lane = tid & 63;
        int r = blockIdx.x * 4 + wid;
        const float4* Ar = (const float4*)(A + (size_t)r * NN);
        float s = 0.f;
#pragma unroll
        for (int i = 0; i < 8; ++i) {
            float4 v = Ar[i * 64 + lane];
            s += v.x + v.y + v.z + v.w;
        }
#pragma unroll
        for (int off = 32; off > 0; off >>= 1) s += __shfl_down(s, off);
        if (lane == 0) dis[r] = (s > 0.f) ? rsqrtf(s) : 0.f;
        return;
    }

    // ---- E[b] 12x12 ----
    int b = blockIdx.x - 512;
    float accr[T1D], accc[T1D];
#pragma unroll
    for (int t = 0; t < T1D; ++t) { accr[t] = 0.f; accc[t] = 0.f; }
    for (int n = tid; n < NN; n += 256) {
        const float* xp = X + ((size_t)b * NN + n) * T1D;
        float x[T1D];
        *(float4*)&x[0] = *(const float4*)&xp[0];
        *(float4*)&x[4] = *(const float4*)&xp[4];
        *(float4*)&x[8] = *(const float4*)&xp[8];
        float u1 = U1[n], u2 = U2[n];
#pragma unroll
        for (int t = 0; t < T1D; ++t) {
            accr[t] += x[t] * u1;
            accc[t] += x[t] * u2;
        }
    }
#pragma unroll
    for (int t = 0; t < T1D; ++t) {
        red[t][tid] = accr[t];
        red[12 + t][tid] = accc[t];
    }
    __syncthreads();
    for (int s = 128; s > 0; s >>= 1) {
        if (tid < s) {
#pragma unroll
            for (int a = 0; a < 24; ++a) red[a][tid] += red[a][tid + s];
        }
        __syncthreads();
    }
    float u3 = U3[0];
    if (tid < T1D) {          // softmax over t per column s
        int s = tid;
        float cs = red[12 + s][0] * u3;
        float vals[T1D];
        float m = -1e30f;
#pragma unroll
        for (int t = 0; t < T1D; ++t) {
            vals[t] = red[t][0] * cs + be[t * T1D + s];
            m = fmaxf(m, vals[t]);
        }
        float sum = 0.f;
#pragma unroll
        for (int t = 0; t < T1D; ++t) { vals[t] = expf(vals[t] - m); sum += vals[t]; }
        float inv = 1.f / sum;
#pragma unroll
        for (int t = 0; t < T1D; ++t) es[t][s] = vals[t] * inv;
    }
    __syncthreads();
    if (tid < T1D) {          // Ve @ es, softmax over t, store E
        int u = tid;
        float vals[T1D];
        float m = -1e30f;
#pragma unroll
        for (int t = 0; t < T1D; ++t) {
            float acc = 0.f;
#pragma unroll
            for (int s = 0; s < T1D; ++s) acc += Ve[t * T1D + s] * es[s][u];
            vals[t] = acc;
            m = fmaxf(m, acc);
        }
        float sum = 0.f;
#pragma unroll
        for (int t = 0; t < T1D; ++t) { vals[t] = expf(vals[t] - m); sum += vals[t]; }
        float inv = 1.f / sum;
#pragma unroll
        for (int t = 0; t < T1D; ++t) E_ws[b * 144 + t * T1D + u] = vals[t] * inv;
    }
}

// ==== dispatch 2: AbT convert (blocks 0..1023) + Xh/Xhbt (1024..1151) ========
__global__ __launch_bounds__(256) void k_mid(const float* __restrict__ A,
                                             const float* __restrict__ dis,
                                             const float* __restrict__ X,
                                             const float* __restrict__ E_ws,
                                             ushort* __restrict__ AbT,
                                             float* __restrict__ Xh,
                                             ushort* __restrict__ Xhbt) {
    __shared__ float lds[5504];
    int t = threadIdx.x;

    if (blockIdx.x < 1024) {
        // ---- AbT[c][k] = bf16(A[k][c]*dis[k]*dis[c]), 64x64 tile ----
        int c0 = (blockIdx.x & 31) * 64, k0 = (blockIdx.x >> 5) * 64;
#pragma unroll
        for (int i = 0; i < 4; ++i) {
            int idx = t + i * 256;           // < 1024
            int kr = idx >> 4, c4 = idx & 15;
            float4 v = *(const float4*)&A[(size_t)(k0 + kr) * NN + c0 + c4 * 4];
            float dk = dis[k0 + kr];
            lds[(c4 * 4 + 0) * 65 + kr] = v.x * dk;
            lds[(c4 * 4 + 1) * 65 + kr] = v.y * dk;
            lds[(c4 * 4 + 2) * 65 + kr] = v.z * dk;
            lds[(c4 * 4 + 3) * 65 + kr] = v.w * dk;
        }
        __syncthreads();
        int cl = t >> 2, ck = (t & 3) * 16;
        float dc = dis[c0 + cl];
        union { ushort us[8]; uint4 v; } p0, p1;
#pragma unroll
        for (int e = 0; e < 8; ++e) p0.us[e] = f2bf(lds[cl * 65 + ck + e] * dc);
#pragma unroll
        for (int e = 0; e < 8; ++e) p1.us[e] = f2bf(lds[cl * 65 + ck + 8 + e] * dc);
        *(uint4*)&AbT[(size_t)(c0 + cl) * NNP + k0 + ck] = p0.v;
        *(uint4*)&AbT[(size_t)(c0 + cl) * NNP + k0 + ck + 8] = p1.v;
        return;
    }

    // ---- Xh[n][b*12+u] + bf16 transpose Xhbt[j][n], 16 n-rows per block ----
    int n0 = (blockIdx.x - 1024) * 16;
    float* EL = lds + 3200;                 // E copy: 2304 floats
#pragma unroll
    for (int i = 0; i < 9; ++i) {
        int idx = t + i * 256;
        if (idx < 2304) EL[idx] = E_ws[idx];
    }
    __syncthreads();
    {
        int nr = t >> 4, b = t & 15;
        const float* xp = X + ((size_t)b * NN + n0 + nr) * T1D;
        float x[T1D];
        *(float4*)&x[0] = *(const float4*)&xp[0];
        *(float4*)&x[4] = *(const float4*)&xp[4];
        *(float4*)&x[8] = *(const float4*)&xp[8];
        const float* Eb = EL + b * 144;
#pragma unroll
        for (int u = 0; u < T1D; ++u) {
            float acc = 0.f;
#pragma unroll
            for (int tt = 0; tt < T1D; ++tt) acc += x[tt] * Eb[tt * T1D + u];
            lds[nr * 200 + b * T1D + u] = acc;
        }
    }
    __syncthreads();
#pragma unroll
    for (int i = 0; i < 3; ++i) {
        int idx4 = t + i * 256;             // < 768
        int row = idx4 / 48, c4 = idx4 % 48;
        *(float4*)&Xh[(size_t)(n0 + row) * JJ + c4 * 4] =
            *(float4*)&lds[row * 200 + c4 * 4];
    }
    if (t < JJ) {
        union { ushort us[8]; uint4 v; } p0, p1;
#pragma unroll
        for (int nr = 0; nr < 8; ++nr) p0.us[nr] = f2bf(lds[nr * 200 + t]);
#pragma unroll
        for (int nr = 0; nr < 8; ++nr) p1.us[nr] = f2bf(lds[(8 + nr) * 200 + t]);
        *(uint4*)&Xhbt[(size_t)t * NNP + n0] = p0.v;
        *(uint4*)&Xhbt[(size_t)t * NNP + n0 + 8] = p1.v;
    }
}

// ==== GEMM core: tile[c0..+16][j0..+48] = sum_k AbT[c][k]*Zbt[j][k] ==========
// grid (128 c-tiles, 4 j-slices) x 512 thr (8 waves); wave w owns K [w*256,+256).
// MODE 0 (G1): write P fp32 + Pbt bf16-transposed.
// MODE 1 (G2): no global P; fused Chebyshev epilogue writes out (4 batches).
template<int MODE>
__global__ __launch_bounds__(512) void k_gemm(const ushort* __restrict__ AbT,
                                              const ushort* __restrict__ Zbt,
                                              float* __restrict__ P,
                                              ushort* __restrict__ Pbt,
                                              const float* __restrict__ P1,
                                              const float* __restrict__ Xh,
                                              const float* __restrict__ Wcheb,
                                              const float* __restrict__ bcheb,
                                              float* __restrict__ out) {
    __shared__ float lds[24 * 260 + 16 * 48];   // padded partials + reduced tile
    float* Pred = lds + 6240;
    int tid = threadIdx.x;
    int wave = tid >> 6, lane = tid & 63;
    int jl = lane & 15;
    int kl = (lane >> 4) * 8;
    int c0 = blockIdx.x * 16;
    int j0 = blockIdx.y * 48;
    int kbase = wave * 256 + kl;

    const ushort* arow = AbT + (size_t)(c0 + jl) * NNP + kbase;
    f32x4 acc[3];
#pragma unroll
    for (int n = 0; n < 3; ++n) acc[n] = (f32x4)0.f;

#pragma unroll
    for (int ch = 0; ch < 8; ++ch) {
        int koff = ch * 32;
        short8 a = *(const short8*)&arow[koff];
        short8 bfr[3];
#pragma unroll
        for (int n = 0; n < 3; ++n)
            bfr[n] = *(const short8*)&Zbt[(size_t)(j0 + n * 16 + jl) * NNP + kbase + koff];
#pragma unroll
        for (int n = 0; n < 3; ++n)
            acc[n] = __builtin_amdgcn_mfma_f32_16x16x32_bf16(a, bfr[n], acc[n], 0, 0, 0);
    }

#pragma unroll
    for (int n = 0; n < 3; ++n)
        *(f32x4*)&lds[(wave * 3 + n) * 260 + (lane << 2)] = acc[n];
    __syncthreads();

    // reduce 8 wave-partials -> Pred[16][48]; G1 also stores P fp32
    for (int o = tid; o < 768; o += 512) {
        int c_idx = o / 48;
        int j_idx = o - c_idx * 48;
        int n = j_idx >> 4, col = j_idx & 15;
        int lidx = ((c_idx >> 2) * 16 + col) * 4 + (c_idx & 3);
        float s = 0.f;
#pragma unroll
        for (int w = 0; w < 8; ++w) s += lds[(w * 3 + n) * 260 + lidx];
        Pred[c_idx * 48 + j_idx] = s;
        if (MODE == 0) P[(size_t)(c0 + c_idx) * JJ + j0 + j_idx] = s;
    }
    __syncthreads();

    if (MODE == 0) {
        // bf16 transpose: Pbt[j0+j][c0..c0+16], 32B per row
        if (tid < 48) {
            union { ushort us[8]; uint4 v; } q0, q1;
#pragma unroll
            for (int e = 0; e < 8; ++e) q0.us[e] = f2bf(Pred[e * 48 + tid]);
#pragma unroll
            for (int e = 0; e < 8; ++e) q1.us[e] = f2bf(Pred[(8 + e) * 48 + tid]);
            *(uint4*)&Pbt[(size_t)(j0 + tid) * NNP + c0] = q0.v;
            *(uint4*)&Pbt[(size_t)(j0 + tid) * NNP + c0 + 8] = q1.v;
        }
    } else {
        // fused out = relu(Xh(W0-W2) - P1*W1 + 2*P2*W2 + bcheb)
        int o = tid & 63, pair = tid >> 6;     // 8 (n,b) pairs per iteration
        const float* W0 = Wcheb;
        const float* W1 = Wcheb + 768;
        const float* W2 = Wcheb + 1536;
        float w0m2[T1D], w1a[T1D], w2a[T1D];
#pragma unroll
        for (int t = 0; t < T1D; ++t) {
            float w2v = W2[t * 64 + o];
            w0m2[t] = W0[t * 64 + o] - w2v;
            w1a[t] = W1[t * 64 + o];
            w2a[t] = 2.f * w2v;
        }
        float bco = bcheb[o];
#pragma unroll
        for (int it = 0; it < 8; ++it) {
            int pi = pair + it * 8;            // 0..63
            int ni = pi >> 2, bi = pi & 3;
            int n = c0 + ni;
            int b = blockIdx.y * 4 + bi;
            const float* xh = Xh + (size_t)n * JJ + b * T1D;
            const float* p1 = P1 + (size_t)n * JJ + b * T1D;
            const float* p2 = Pred + ni * 48 + bi * T1D;
            float a = bco;
#pragma unroll
            for (int t = 0; t < T1D; ++t)
                a += xh[t] * w0m2[t] - p1[t] * w1a[t] + p2[t] * w2a[t];
            out[(size_t)((b << 11) + n) * 64 + o] = fmaxf(a, 0.f);
        }
    }
}

extern "C" void kernel_launch(void* const* d_in, const int* in_sizes, int n_in,
                              void* d_out, int out_size, void* d_ws, size_t ws_size,
                              hipStream_t stream) {
    const float* X  = (const float*)d_in[0];
    const float* A  = (const float*)d_in[1];
    // d_in[2]=Vs, d_in[3]=bs, d_in[4]=W1, d_in[5]=W2, d_in[6]=W3 : dead code
    const float* Ve = (const float*)d_in[7];
    const float* be = (const float*)d_in[8];
    const float* U1 = (const float*)d_in[9];
    const float* U2 = (const float*)d_in[10];
    const float* U3 = (const float*)d_in[11];
    const float* Wc = (const float*)d_in[12];
    const float* bc = (const float*)d_in[13];
    float* out = (float*)d_out;

    float* w     = (float*)d_ws;
    float* dis   = w + OFF_DIS;
    float* E     = w + OFF_E;
    float* Xh    = w + OFF_XH;
    float* P1    = w + OFF_P1;
    ushort* Xhbt = (ushort*)(w + OFF_XHBT);
    ushort* P1bt = (ushort*)(w + OFF_P1BT);
    ushort* AbT  = (ushort*)(w + OFF_ABT);

    k_degE<<<528, 256, 0, stream>>>(A, X, U1, U2, U3, be, Ve, dis, E);
    k_mid<<<1152, 256, 0, stream>>>(A, dis, X, E, AbT, Xh, Xhbt);
    k_gemm<0><<<dim3(128, 4), 512, 0, stream>>>(AbT, Xhbt, P1, P1bt,
                                                nullptr, nullptr, nullptr, nullptr, nullptr);
    k_gemm<1><<<dim3(128, 4), 512, 0, stream>>>(AbT, P1bt, nullptr, nullptr,
                                                P1, Xh, Wc, bc, out);
}